// Round 1
// baseline (8228.363 us; speedup 1.0000x reference)
//
#include <hip/hip_runtime.h>
#include <hip/hip_bf16.h>
#include <math.h>

// LSTM: S=512, B=64, I=1024, H=1024
// Inputs: x[S,B,I], h0[B,H], c0[B,H], W_ih[4H,I], b_ih[4H], W_hh[4H,H], b_hh[4H]
// Output: out[S,B,H] fp32, then h_last[B,H], c_last[B,H]
//
// Strategy: bf16 MFMA for both GEMMs (fp32 accum), fp32 pointwise/cell state.
//  1) convert x,W_ih,W_hh,h0 -> bf16 in ws
//  2) gates_x[S*B,4H] = x_bf16 @ W_ih_bf16^T  (128x128 tile MFMA GEMM, bf16 out)
//  3) 512x step kernel: gates = gates_x[t] + bias + h@W_hh^T; pointwise; h,c update
//  4) tail copy h_last/c_last

#define S_LEN 512
#define BATCH 64
#define IDIM 1024
#define HDIM 1024
#define GDIM 4096   // 4*H

typedef __bf16 bf16x8 __attribute__((ext_vector_type(8)));
typedef float f32x4 __attribute__((ext_vector_type(4)));

__device__ inline ushort f2b(float f) {
    union { float f; unsigned u; } v; v.f = f;
    unsigned u = v.u;
    unsigned r = (u + 0x7fffu + ((u >> 16) & 1u)) >> 16;
    return (ushort)r;
}
__device__ inline float b2f(ushort u) {
    union { unsigned u; float f; } v; v.u = ((unsigned)u) << 16;
    return v.f;
}
__device__ inline float sigmoidf_(float x) { return 1.f / (1.f + __expf(-x)); }
__device__ inline float tanhf_(float x) {
    // stable: 1 - 2/(e^{2x}+1)
    return 1.f - 2.f / (__expf(2.f * x) + 1.f);
}

// ---------- conversion kernels ----------
__global__ __launch_bounds__(256) void f2b_kernel(ushort* __restrict__ dst,
                                                  const float* __restrict__ src, int n) {
    int i = (blockIdx.x * 256 + threadIdx.x) * 4;
    if (i < n) {
        float4 v = *(const float4*)(src + i);
        ushort4 o;
        o.x = f2b(v.x); o.y = f2b(v.y); o.z = f2b(v.z); o.w = f2b(v.w);
        *(ushort4*)(dst + i) = o;
    }
}

__global__ __launch_bounds__(256) void bias_kernel(float* __restrict__ bias,
                                                   const float* __restrict__ b_ih,
                                                   const float* __restrict__ b_hh) {
    int i = blockIdx.x * 256 + threadIdx.x;
    if (i < GDIM) bias[i] = b_ih[i] + b_hh[i];
}

// ---------- big GEMM: C[M,N] = A[M,K] @ B[N,K]^T, all bf16, fp32 accum ----------
// M=32768, N=4096, K=1024. Tile 128x128, BK=64, 256 threads (4 waves 2x2 of 64x64).
#define LDSS 72  // 64 + 8 pad (keeps 16B alignment: 144B row stride)
__global__ __launch_bounds__(256) void gemm_bt_kernel(const ushort* __restrict__ A,
                                                      const ushort* __restrict__ B,
                                                      ushort* __restrict__ C,
                                                      int M, int N, int K) {
    __shared__ __align__(16) ushort As[128 * LDSS];
    __shared__ __align__(16) ushort Bs[128 * LDSS];
    const int tid = threadIdx.x;
    const int lane = tid & 63;
    const int wave = tid >> 6;
    const int l15 = lane & 15;
    const int quad = lane >> 4;
    const int bn = blockIdx.x;   // N/128
    const int bm = blockIdx.y;   // M/128
    const int wrow = (wave & 1) * 64;
    const int wcol = (wave >> 1) * 64;

    f32x4 acc[4][4] = {};

    for (int kt = 0; kt < K; kt += 64) {
        #pragma unroll
        for (int i = 0; i < 4; i++) {
            int chunk = tid + i * 256;       // 0..1023
            int r = chunk >> 3;
            int c8 = (chunk & 7) * 8;
            *(uint4*)&As[r * LDSS + c8] =
                *(const uint4*)&A[(size_t)(bm * 128 + r) * K + kt + c8];
            *(uint4*)&Bs[r * LDSS + c8] =
                *(const uint4*)&B[(size_t)(bn * 128 + r) * K + kt + c8];
        }
        __syncthreads();
        #pragma unroll
        for (int kc = 0; kc < 2; kc++) {
            const int ko = kc * 32 + quad * 8;
            bf16x8 af[4], bf[4];
            #pragma unroll
            for (int m = 0; m < 4; m++)
                af[m] = *(const bf16x8*)&As[(wrow + m * 16 + l15) * LDSS + ko];
            #pragma unroll
            for (int n = 0; n < 4; n++)
                bf[n] = *(const bf16x8*)&Bs[(wcol + n * 16 + l15) * LDSS + ko];
            #pragma unroll
            for (int m = 0; m < 4; m++)
                #pragma unroll
                for (int n = 0; n < 4; n++)
                    acc[m][n] = __builtin_amdgcn_mfma_f32_16x16x32_bf16(af[m], bf[n], acc[m][n], 0, 0, 0);
        }
        __syncthreads();
    }
    // epilogue: D layout col=lane&15, row=quad*4+reg
    const int col0 = bn * 128 + wcol;
    const int row0 = bm * 128 + wrow;
    #pragma unroll
    for (int m = 0; m < 4; m++) {
        #pragma unroll
        for (int n = 0; n < 4; n++) {
            int col = col0 + n * 16 + l15;
            int rbase = row0 + m * 16 + quad * 4;
            #pragma unroll
            for (int r = 0; r < 4; r++)
                C[(size_t)(rbase + r) * N + col] = f2b(acc[m][n][r]);
        }
    }
}

// ---------- per-step kernel ----------
// 64 blocks; block hg handles h-cols [hg*16, hg*16+16) for all 4 gates, all 64 batches.
// 4 waves: wave g computes gate g: M=64 x N=16 over K=1024. Then LDS exchange + pointwise.
__global__ __launch_bounds__(256) void lstm_step_kernel(
    const ushort* __restrict__ gx,      // gates_x[t]: [64][4096] bf16
    const ushort* __restrict__ hprev,   // [64][1024] bf16
    ushort* __restrict__ hnext,         // [64][1024] bf16
    const ushort* __restrict__ Whh,     // [4096][1024] bf16
    const float* __restrict__ bias,     // [4096]
    float* __restrict__ c_ws,           // [64][1024] fp32 (in-place)
    float* __restrict__ out_t)          // [64][1024] fp32
{
    __shared__ __align__(16) ushort Hs[64 * LDSS];
    __shared__ __align__(16) ushort Ws[64 * LDSS];
    __shared__ float Gs[4 * 64 * 16];

    const int tid = threadIdx.x;
    const int lane = tid & 63;
    const int gate = tid >> 6;   // wave id = gate
    const int l15 = lane & 15;
    const int quad = lane >> 4;
    const int hg = blockIdx.x;   // 0..63

    f32x4 acc[4] = {};

    for (int kt = 0; kt < HDIM; kt += 64) {
        #pragma unroll
        for (int i = 0; i < 2; i++) {
            int chunk = tid + i * 256;   // 0..511
            int r = chunk >> 3;
            int c8 = (chunk & 7) * 8;
            *(uint4*)&Hs[r * LDSS + c8] =
                *(const uint4*)&hprev[(size_t)r * HDIM + kt + c8];
            int g = r >> 4, ri = r & 15;
            *(uint4*)&Ws[r * LDSS + c8] =
                *(const uint4*)&Whh[((size_t)g * 1024 + hg * 16 + ri) * HDIM + kt + c8];
        }
        __syncthreads();
        #pragma unroll
        for (int kc = 0; kc < 2; kc++) {
            const int ko = kc * 32 + quad * 8;
            bf16x8 bfr = *(const bf16x8*)&Ws[(gate * 16 + l15) * LDSS + ko];
            #pragma unroll
            for (int m = 0; m < 4; m++) {
                bf16x8 afr = *(const bf16x8*)&Hs[(m * 16 + l15) * LDSS + ko];
                acc[m] = __builtin_amdgcn_mfma_f32_16x16x32_bf16(afr, bfr, acc[m], 0, 0, 0);
            }
        }
        __syncthreads();
    }

    // write pre-activations to Gs: element (b = m*16 + quad*4 + r, hc = l15)
    #pragma unroll
    for (int m = 0; m < 4; m++) {
        #pragma unroll
        for (int r = 0; r < 4; r++) {
            int b = m * 16 + quad * 4 + r;
            Gs[(gate * 64 + b) * 16 + l15] = acc[m][r];
        }
    }
    __syncthreads();

    // pointwise: 1024 elements (64 b x 16 hc), 4 per thread
    #pragma unroll
    for (int e = 0; e < 4; e++) {
        int idx = tid + e * 256;
        int b = idx >> 4;
        int hc = idx & 15;
        int hcg = hg * 16 + hc;
        float g0 = Gs[(0 * 64 + b) * 16 + hc] + bias[0 * 1024 + hcg] + b2f(gx[(size_t)b * GDIM + 0 * 1024 + hcg]);
        float g1 = Gs[(1 * 64 + b) * 16 + hc] + bias[1 * 1024 + hcg] + b2f(gx[(size_t)b * GDIM + 1 * 1024 + hcg]);
        float g2 = Gs[(2 * 64 + b) * 16 + hc] + bias[2 * 1024 + hcg] + b2f(gx[(size_t)b * GDIM + 2 * 1024 + hcg]);
        float g3 = Gs[(3 * 64 + b) * 16 + hc] + bias[3 * 1024 + hcg] + b2f(gx[(size_t)b * GDIM + 3 * 1024 + hcg]);
        float ig = sigmoidf_(g0);
        float fg = sigmoidf_(g1);
        float gg = tanhf_(g2);
        float og = sigmoidf_(g3);
        float c_old = c_ws[(size_t)b * HDIM + hcg];
        float cn = fg * c_old + ig * gg;
        c_ws[(size_t)b * HDIM + hcg] = cn;
        float hn = og * tanhf_(cn);
        out_t[(size_t)b * HDIM + hcg] = hn;
        hnext[(size_t)b * HDIM + hcg] = f2b(hn);
    }
}

// ---------- tail: h_last, c_last ----------
__global__ __launch_bounds__(256) void tail_kernel(float* __restrict__ dst,
                                                   const float* __restrict__ hlast,
                                                   const float* __restrict__ c_ws) {
    int i = blockIdx.x * 256 + threadIdx.x;
    if (i < BATCH * HDIM) {
        dst[i] = hlast[i];
        dst[BATCH * HDIM + i] = c_ws[i];
    }
}

extern "C" void kernel_launch(void* const* d_in, const int* in_sizes, int n_in,
                              void* d_out, int out_size, void* d_ws, size_t ws_size,
                              hipStream_t stream) {
    const float* x    = (const float*)d_in[0];
    const float* h0   = (const float*)d_in[1];
    const float* c0   = (const float*)d_in[2];
    const float* W_ih = (const float*)d_in[3];
    const float* b_ih = (const float*)d_in[4];
    const float* W_hh = (const float*)d_in[5];
    const float* b_hh = (const float*)d_in[6];
    float* out = (float*)d_out;

    // workspace layout (bytes)
    const size_t n_x  = (size_t)S_LEN * BATCH * IDIM;        // 33,554,432
    const size_t n_w  = (size_t)GDIM * IDIM;                 //  4,194,304
    const size_t o_xb   = 0;
    const size_t o_gx   = o_xb + n_x * 2;                    //  64 MiB
    const size_t o_wih  = o_gx + (size_t)S_LEN * BATCH * GDIM * 2;  // +256 MiB
    const size_t o_whh  = o_wih + n_w * 2;
    const size_t o_bias = o_whh + n_w * 2;
    const size_t o_h0   = o_bias + GDIM * 4;
    const size_t o_h1   = o_h0 + (size_t)BATCH * HDIM * 2;
    const size_t o_c    = o_h1 + (size_t)BATCH * HDIM * 2;
    const size_t total  = o_c + (size_t)BATCH * HDIM * 4;
    if (ws_size < total) return;  // fail visibly rather than corrupt memory

    char* ws = (char*)d_ws;
    ushort* xb   = (ushort*)(ws + o_xb);
    ushort* gx   = (ushort*)(ws + o_gx);
    ushort* wihb = (ushort*)(ws + o_wih);
    ushort* whhb = (ushort*)(ws + o_whh);
    float*  bias = (float*)(ws + o_bias);
    ushort* hbuf[2] = { (ushort*)(ws + o_h0), (ushort*)(ws + o_h1) };
    float*  c_ws = (float*)(ws + o_c);

    // 1) conversions
    f2b_kernel<<<(int)(n_x / 1024), 256, 0, stream>>>(xb, x, (int)n_x);
    f2b_kernel<<<(int)(n_w / 1024), 256, 0, stream>>>(wihb, W_ih, (int)n_w);
    f2b_kernel<<<(int)(n_w / 1024), 256, 0, stream>>>(whhb, W_hh, (int)n_w);
    f2b_kernel<<<(BATCH * HDIM) / 1024, 256, 0, stream>>>(hbuf[0], h0, BATCH * HDIM);
    bias_kernel<<<GDIM / 256, 256, 0, stream>>>(bias, b_ih, b_hh);
    hipMemcpyAsync(c_ws, c0, (size_t)BATCH * HDIM * 4, hipMemcpyDeviceToDevice, stream);

    // 2) gates_x = x @ W_ih^T  (M=32768, N=4096, K=1024)
    {
        dim3 grid(GDIM / 128, (S_LEN * BATCH) / 128);
        gemm_bt_kernel<<<grid, 256, 0, stream>>>(xb, wihb, gx, S_LEN * BATCH, GDIM, IDIM);
    }

    // 3) recurrence
    for (int t = 0; t < S_LEN; t++) {
        const ushort* gxt = gx + (size_t)t * BATCH * GDIM;
        float* out_t = out + (size_t)t * BATCH * HDIM;
        lstm_step_kernel<<<64, 256, 0, stream>>>(gxt, hbuf[t & 1], hbuf[(t + 1) & 1],
                                                 whhb, bias, c_ws, out_t);
    }

    // 4) tail
    tail_kernel<<<(BATCH * HDIM) / 256, 256, 0, stream>>>(
        out + (size_t)S_LEN * BATCH * HDIM,
        out + (size_t)(S_LEN - 1) * BATCH * HDIM,
        c_ws);
}